// Round 2
// 266.723 us; speedup vs baseline: 1.0797x; 1.0797x over previous
//
#include <hip/hip_runtime.h>

// StackLSTMCell: B=256, IN=256, H=256, L=2, S=128 (SLOTS=129). All f32.
// Fused-overlap structure:
//   K1 gemm_copy_k : blocks[0,256) gemm0; blocks[256,2304) copy hid stack
//   K2 act0_copy_k : blocks[0,256) act0;  blocks[256,1280) copy cel chunk1
//   K3 gemm_copy_k : blocks[0,256) gemm1; blocks[256,2304) copy cel rest
//   K4 slot_k      : 256 blocks write pos+1 slot in both stacks + finalize
// The passthrough copy has no dependency on the compute, so it rides in the
// same dispatches and absorbs the GEMM's latency stalls with HBM streaming.

static __device__ __forceinline__ float sigf(float x) {
    return 1.0f / (1.0f + __expf(-x));
}
static __device__ __forceinline__ float tanh_fast(float x) {
    return 2.0f / (1.0f + __expf(-2.0f * x)) - 1.0f;
}

#define GBM 16
#define GBN 64
#define GBK 32

#define NV4_PER_STACK 4227072     // 129*256*256*2/4 float4 per stack
#define STACK_ELEMS   16908288    // 129*256*256*2
#define CEL_CHUNK1    655360      // float4 of cel stack copied during act0

// grid-stride passthrough copy for blocks [cb0, gridDim.x)
static __device__ __forceinline__ void copy_span(
    int cb0, const float4* __restrict__ csrc, float4* __restrict__ cdst, int cn4)
{
    int stride = (gridDim.x - cb0) * 256;
    for (int i = (blockIdx.x - cb0) * 256 + threadIdx.x; i < cn4; i += stride)
        cdst[i] = csrc[i];
}

// ---------------------------------------------------------------------------
// GEMM: gates(256x1024) = A(256x512) @ [w_ih | w_hh]^T + b_ih + b_hh
// A row b: k<256 -> a_lo[b*256+k]; k>=256 -> a_hi gather (stride 2) at pos[b].
// Tiling: BM=16 x BN=64 x BK=32, blocks [0,256) = 16x16 tiles, 256 threads.
// Blocks >= 256 are passthrough-copy workers.
__global__ __launch_bounds__(256) void gemm_copy_k(
    const float* __restrict__ a_lo,    // 256 x 256, stride 1
    const float* __restrict__ a_hi,    // hid + l    (stride 2 gather at pos)
    const int*   __restrict__ pos,
    const float* __restrict__ wih,     // 1024 x 256
    const float* __restrict__ whh,     // 1024 x 256
    const float* __restrict__ bih,
    const float* __restrict__ bhh,
    float* __restrict__ gates,
    const float4* __restrict__ csrc,   // copy task
    float4* __restrict__ cdst,
    int cn4)
{
    if (blockIdx.x >= 256) {           // copy worker block
        copy_span(256, csrc, cdst, cn4);
        return;
    }
    __shared__ float As[GBK][GBM + 1];   // row stride 17 floats
    __shared__ float Ws[GBK][GBN + 4];   // row stride 68 floats (16B aligned)
    int t   = threadIdx.x;
    int bm0 = (blockIdx.x >> 4) * GBM;
    int jt0 = (blockIdx.x & 15) * GBN;
    // staging assignments
    int arow = t >> 4;            // 0..15
    int akk  = (t & 15) * 2;      // 0..30 (float2 of k)
    int wrow = t >> 2;            // 0..63
    int wkb  = (t & 3) * 8;       // 0,8,16,24
    // compute assignments
    int tx = t & 15, ty = t >> 4;
    int ab = bm0 + arow;
    int ap = pos[ab];
    int wj = jt0 + wrow;

    float2 apre;
    float4 wpre0, wpre1;
    {   // prefetch tile kt=0
        int k = akk;              // < 256 always at kt=0
        apre = *(const float2*)&a_lo[ab * 256 + k];
        const float* ws = &wih[wj * 256 + wkb];
        wpre0 = *(const float4*)ws;
        wpre1 = *(const float4*)(ws + 4);
    }
    float acc[4] = {0.f, 0.f, 0.f, 0.f};
    for (int kt = 0; kt < 512; kt += GBK) {
        __syncthreads();
        As[akk][arow]     = apre.x;
        As[akk + 1][arow] = apre.y;
        Ws[wkb][wrow]     = wpre0.x;
        Ws[wkb + 1][wrow] = wpre0.y;
        Ws[wkb + 2][wrow] = wpre0.z;
        Ws[wkb + 3][wrow] = wpre0.w;
        Ws[wkb + 4][wrow] = wpre1.x;
        Ws[wkb + 5][wrow] = wpre1.y;
        Ws[wkb + 6][wrow] = wpre1.z;
        Ws[wkb + 7][wrow] = wpre1.w;
        int kt2 = kt + GBK;
        if (kt2 < 512) {          // prefetch next tile; latency hides under FMA
            int k = kt2 + akk;
            if (k < 256) {
                apre = *(const float2*)&a_lo[ab * 256 + k];
            } else {
                const float* ah = a_hi + ((ap * 256 + ab) * 256 + (k - 256)) * 2;
                apre.x = ah[0];
                apre.y = ah[2];
            }
            int kk = kt2 + wkb;
            const float* ws = (kk < 256) ? &wih[wj * 256 + kk]
                                         : &whh[wj * 256 + kk - 256];
            wpre0 = *(const float4*)ws;
            wpre1 = *(const float4*)(ws + 4);
        }
        __syncthreads();
        #pragma unroll
        for (int k = 0; k < GBK; ++k) {
            float a   = As[k][ty];
            float4 bv = *(const float4*)&Ws[k][tx * 4];
            acc[0] = fmaf(a, bv.x, acc[0]);
            acc[1] = fmaf(a, bv.y, acc[1]);
            acc[2] = fmaf(a, bv.z, acc[2]);
            acc[3] = fmaf(a, bv.w, acc[3]);
        }
    }
    int j = jt0 + tx * 4;
    float4 b0 = *(const float4*)&bih[j];
    float4 b1 = *(const float4*)&bhh[j];
    float4 r;
    r.x = acc[0] + b0.x + b1.x;
    r.y = acc[1] + b0.y + b1.y;
    r.z = acc[2] + b0.z + b1.z;
    r.w = acc[3] + b0.w + b1.w;
    *(float4*)&gates[(bm0 + ty) * 1024 + j] = r;
}

// ---------------------------------------------------------------------------
// Layer-0 activation (blocks [0,256)) + cel-stack copy chunk (blocks >= 256).
__global__ __launch_bounds__(256) void act0_copy_k(
    const float* __restrict__ gates,
    const float* __restrict__ cel,
    const int*   __restrict__ pos,
    float* __restrict__ h0f, float* __restrict__ c0f,
    const float4* __restrict__ csrc,
    float4* __restrict__ cdst,
    int cn4)
{
    if (blockIdx.x >= 256) {
        copy_span(256, csrc, cdst, cn4);
        return;
    }
    int e = blockIdx.x * 256 + threadIdx.x;   // 65536 = B*H
    int b = e >> 8, h = e & 255;
    float cin = cel[((pos[b] * 256 + b) * 256 + h) * 2];   // l=0
    const float* g = gates + b * 1024 + h;
    float gi = g[0], gf = g[256], gg = g[512], go = g[768];
    float c  = sigf(gf) * cin + sigf(gi) * tanh_fast(gg);
    h0f[e] = sigf(go) * tanh_fast(c);
    c0f[e] = c;
}

// ---------------------------------------------------------------------------
// Write the freshly-computed pos+1 slot into both output stacks (overwrites
// the stale passthrough data) + finalize block for h_out/c_out.
static __device__ __forceinline__ void lstm1(
    const float* __restrict__ gates, const float* __restrict__ cel,
    int p, int b, int h, float& hv, float& cv)
{
    float cin = cel[((p * 256 + b) * 256 + h) * 2 + 1];    // l=1
    const float* g = gates + b * 1024 + h;
    float gi = g[0], gf = g[256], gg = g[512], go = g[768];
    cv = sigf(gf) * cin + sigf(gi) * tanh_fast(gg);
    hv = sigf(go) * tanh_fast(cv);
}

__global__ __launch_bounds__(256) void slot_k(
    const float* __restrict__ hid, const float* __restrict__ cel,
    const int* __restrict__ pos, const int* __restrict__ op,
    const float* __restrict__ h0f, const float* __restrict__ c0f,
    const float* __restrict__ gates,     // layer-1 gates
    float* __restrict__ out)
{
    if (blockIdx.x == 256) {
        // finalize: h_out (1,B,L) at out[0..511], c_out at out[512..1023]
        int b = threadIdx.x;
        int o = op[b];
        int p = pos[b];
        float h0v, h1v, c0v, c1v;
        if (o == 1) {            // new_pos == pos+1: freshly computed slot
            h0v = h0f[b * 256 + 255];
            c0v = c0f[b * 256 + 255];
            lstm1(gates, cel, p, b, 255, h1v, c1v);
        } else {                 // untouched slot: passthrough from input
            int base2 = (((p + o) * 256 + b) * 256 + 255) * 2;
            h0v = hid[base2]; h1v = hid[base2 + 1];
            c0v = cel[base2]; c1v = cel[base2 + 1];
        }
        out[b * 2]           = h0v;
        out[b * 2 + 1]       = h1v;
        out[512 + b * 2]     = c0v;
        out[512 + b * 2 + 1] = c1v;
        return;
    }
    int v = blockIdx.x * 256 + threadIdx.x;   // 0..65535 float4 of slot data
    bool is_cell = v >= 32768;
    int vv = v & 32767;
    int b = vv >> 7;            // 128 float4 per b-plane within a slot
    int q = vv & 127;           // elems (h=2q..2q+1, l=0..1)
    int p = pos[b];
    int h = q * 2;
    float h1a, c1a, h1b, c1b;
    lstm1(gates, cel, p, b, h,     h1a, c1a);
    lstm1(gates, cel, p, b, h + 1, h1b, c1b);
    float4 val;
    if (is_cell) {
        val.x = c0f[b * 256 + h];     val.y = c1a;
        val.z = c0f[b * 256 + h + 1]; val.w = c1b;
    } else {
        val.x = h0f[b * 256 + h];     val.y = h1a;
        val.z = h0f[b * 256 + h + 1]; val.w = h1b;
    }
    float4* dst = (float4*)(out + 1024 + (is_cell ? STACK_ELEMS : 0));
    dst[(p + 1) * 32768 + b * 128 + q] = val;
}

// ---------------------------------------------------------------------------
extern "C" void kernel_launch(void* const* d_in, const int* in_sizes, int n_in,
                              void* d_out, int out_size, void* d_ws, size_t ws_size,
                              hipStream_t stream) {
    const float* x    = (const float*)d_in[0];
    const float* hid  = (const float*)d_in[1];
    const float* cel  = (const float*)d_in[2];
    const float* wih0 = (const float*)d_in[3];
    const float* whh0 = (const float*)d_in[4];
    const float* bih0 = (const float*)d_in[5];
    const float* bhh0 = (const float*)d_in[6];
    const float* wih1 = (const float*)d_in[7];
    const float* whh1 = (const float*)d_in[8];
    const float* bih1 = (const float*)d_in[9];
    const float* bhh1 = (const float*)d_in[10];
    const int* op  = (const int*)d_in[11];
    const int* pos = (const int*)d_in[12];
    float* out = (float*)d_out;

    // workspace: gates 256x1024, h0f 256x256, c0f 256x256 (f32)
    float* W     = (float*)d_ws;
    float* gates = W;
    float* h0f   = W + 262144;
    float* c0f   = W + 327680;

    float4*       hid_out = (float4*)(out + 1024);
    float4*       cel_out = (float4*)(out + 1024 + STACK_ELEMS);
    const float4* hid_in  = (const float4*)hid;
    const float4* cel_in  = (const float4*)cel;

    // K1: gemm0 + passthrough copy of the entire hidden stack
    gemm_copy_k<<<256 + 2048, 256, 0, stream>>>(
        x, hid, pos, wih0, whh0, bih0, bhh0, gates,
        hid_in, hid_out, NV4_PER_STACK);
    // K2: act0 + first chunk of the cell-stack copy
    act0_copy_k<<<256 + 1024, 256, 0, stream>>>(
        gates, cel, pos, h0f, c0f,
        cel_in, cel_out, CEL_CHUNK1);
    // K3: gemm1 + remainder of the cell-stack copy
    gemm_copy_k<<<256 + 2048, 256, 0, stream>>>(
        h0f, hid + 1, pos, wih1, whh1, bih1, bhh1, gates,
        cel_in + CEL_CHUNK1, cel_out + CEL_CHUNK1,
        NV4_PER_STACK - CEL_CHUNK1);
    // K4: overwrite pos+1 slot in both output stacks + finalize h_out/c_out
    slot_k<<<257, 256, 0, stream>>>(
        hid, cel, pos, op, h0f, c0f, gates, out);
}